// Round 14
// baseline (73.490 us; speedup 1.0000x reference)
//
#include <hip/hip_runtime.h>

#define BB 4096
#define TT 80
#define VV 10000
#define EE 100
#define HH 64

typedef _Float16 f16x8 __attribute__((ext_vector_type(8)));
typedef _Float16 f16x4 __attribute__((ext_vector_type(4)));
typedef __attribute__((ext_vector_type(4))) float f4v;   // 4 fp32

// Transposed compute: D = A(W^T frag) * B(state frag) + C -> lane holds
// (batch row = l&15, 4 adjacent hidden cols per tile = 4*(l>>4)+q)
#define MFMA(w, s, c) __builtin_amdgcn_mfma_f32_16x16x32_f16((w), (s), (c), 0, 0, 0)

// tanh(x) = 1 - 2/(exp(2x)+1). +inf -> 1, -inf -> -1.
__device__ __forceinline__ float fast_tanh(float x) {
    float e = __builtin_amdgcn_exp2f(x * 2.8853900817779268f); // exp(2x)
    return 1.0f - 2.0f * __builtin_amdgcn_rcpf(e + 1.0f);
}

// pi-PERMUTED hi-only weight A-fragment: slot (g,i) <- W[k][c] with
//   k = pi(kf,g,i) = 16*(i>>1) + 4*g + 2*kf + (i&1)
// (bijection -> contraction unchanged). Chosen so the D values a lane holds
// (cols 16t+4g+q) ARE its own next-step B-fragment slots -- the recurrence
// needs no cross-lane motion and no LDS. Layout validated end-to-end in R11
// (passed); hi-only validated in R13 (passed).
__device__ __forceinline__ f16x8 load_wfrag_pi_hi(const float* __restrict__ W,
                                                  int kf, int g, int c) {
    union { _Float16 h[8]; f16x8 v; } th;
#pragma unroll
    for (int i = 0; i < 8; ++i) {
        int k = 16 * (i >> 1) + 4 * g + 2 * kf + (i & 1);
        th.h[i] = (_Float16)W[k * HH + c];
    }
    return th.v;
}

// emb2h[v][j] = fp16( b0[j] + sum_e emb[v][e] * Wx0[e][j] )  (unchanged, proven)
__global__ __launch_bounds__(256) void emb2_kernel(const float* __restrict__ emb,
                                                   const float* __restrict__ Wx0,
                                                   const float* __restrict__ b0,
                                                   _Float16* __restrict__ emb2h) {
    const int tid = threadIdx.x;
    const int wid = tid >> 6;
    const int l = tid & 63;
    const int g = l >> 4;
    const int r16 = l & 15;
    const int c = 16 * wid + r16;
    const int jcol = 16 * wid + 4 * g;
    const int vr = blockIdx.x * 16 + r16;   // VV % 16 == 0

    f16x8 wa[4];   // Wx0^T hi frags, K = 128 (zero-pad e >= 100)
#pragma unroll
    for (int kf = 0; kf < 4; ++kf) {
        union { _Float16 h[8]; f16x8 v; } t;
#pragma unroll
        for (int i = 0; i < 8; ++i) {
            int e = 32 * kf + 8 * g + i;
            t.h[i] = (e < EE) ? (_Float16)Wx0[e * HH + c] : (_Float16)0.f;
        }
        wa[kf] = t.v;
    }
    const float* er = emb + (size_t)vr * EE;
    f4v acc = *(const f4v*)&b0[jcol];
#pragma unroll
    for (int kf = 0; kf < 4; ++kf) {
        union { _Float16 h[8]; f16x8 v; } tb;
#pragma unroll
        for (int i = 0; i < 8; ++i) {
            int e = 32 * kf + 8 * g + i;
            tb.h[i] = (e < EE) ? (_Float16)er[e] : (_Float16)0.f;
        }
        acc = MFMA(wa[kf], tb.v, acc);
    }
    f16x4 o;
#pragma unroll
    for (int q = 0; q < 4; ++q) o[q] = (_Float16)acc[q];
    *(f16x4*)&emb2h[(size_t)vr * HH + jcol] = o;
}

// Single-wave fully-fused chain: 256 blocks x 64 threads (1 wave = 1 row-group
// of 16 batch rows). The ENTIRE two-layer recurrence lives in this wave's
// registers via the pi-layout:
//   step p: h0(p) = tanh(x(p) + Wh0^T h0(p-1))   [8 MFMA, frags in-register]
//           h1(p) = tanh(b1 + Wx1^T h0(p) + Wh1^T h1(p-1))   [16 MFMA]
// ZERO barriers, ZERO LDS state traffic (tokens staged once, wave-coherent).
// All register arrays fully unrolled / statically indexed (R11 lesson).
__global__ __launch_bounds__(64, 1) void rnn_chain(
    const int* __restrict__ tokens, const _Float16* __restrict__ emb2,
    const float* __restrict__ Wh0, const float* __restrict__ Wx1,
    const float* __restrict__ Wh1, const float* __restrict__ b1,
    const float* __restrict__ Wout, const float* __restrict__ bout,
    float* __restrict__ out) {
    __shared__ int tokB[TT][16];   // [t][row], byte-scaled (<<7)

    const int l = threadIdx.x;     // 0..63
    const int g = l >> 4;
    const int r16 = l & 15;        // my batch row
    const int R = blockIdx.x * 16;

    for (int i = l; i < 16 * TT; i += 64) {
        int r = i / TT, t = i - r * TT;
        tokB[t][r] = tokens[R * TT + i] << 7;   // row stride 64 fp16 = 128 B
    }
    // same wave writes & reads tokB -> no barrier needed (lgkm ordering only)

    f16x8 w0[4][2], wx[4][2], w1[4][2];
    f4v b1v[4];
#pragma unroll
    for (int t = 0; t < 4; ++t) {
        int c = 16 * t + r16;
        w0[t][0] = load_wfrag_pi_hi(Wh0, 0, g, c);
        w0[t][1] = load_wfrag_pi_hi(Wh0, 1, g, c);
        wx[t][0] = load_wfrag_pi_hi(Wx1, 0, g, c);
        wx[t][1] = load_wfrag_pi_hi(Wx1, 1, g, c);
        w1[t][0] = load_wfrag_pi_hi(Wh1, 0, g, c);
        w1[t][1] = load_wfrag_pi_hi(Wh1, 1, g, c);
        b1v[t] = *(const f4v*)&b1[16 * t + 4 * g];
    }
    const f4v z4 = {0.f, 0.f, 0.f, 0.f};
    const char* eb = (const char*)emb2 + (size_t)(4 * g) * 2;

    f16x8 f0h = (f16x8)0, f1h = (f16x8)0;   // h0(p-1) B-frags (kf0, kf1)
    f16x8 f0g = (f16x8)0, f1g = (f16x8)0;   // h1(p-1) B-frags
    f4v vv[4];                               // last h1 tanh values (f32)

    f16x4 xcs[4], xns[4];
    {
        int tb = tokB[0][r16];
#pragma unroll
        for (int t = 0; t < 4; ++t)
            xcs[t] = *(const f16x4*)(eb + tb + 32 * t);
    }

#pragma unroll 1
    for (int p = 0; p < TT; ++p) {
        // prefetch x(p+1) (clamped); latency hides under this step's compute
        int pn = (p + 1 < TT) ? p + 1 : TT - 1;
        int tbn = tokB[pn][r16];
#pragma unroll
        for (int t = 0; t < 4; ++t)
            xns[t] = *(const f16x4*)(eb + tbn + 32 * t);

        // ---- h0(p) = tanh(x(p) + Wh0^T h0(p-1)) ----  (p=0: frags are 0)
        union PK { _Float16 h[8]; f16x8 v; } p0, p1;
#pragma unroll
        for (int t = 0; t < 4; ++t) {
            f4v a = {(float)xcs[t][0], (float)xcs[t][1],
                     (float)xcs[t][2], (float)xcs[t][3]};
            a = MFMA(w0[t][0], f0h, a);
            a = MFMA(w0[t][1], f1h, a);
            p0.h[2 * t]     = (_Float16)fast_tanh(a[0]);
            p0.h[2 * t + 1] = (_Float16)fast_tanh(a[1]);
            p1.h[2 * t]     = (_Float16)fast_tanh(a[2]);
            p1.h[2 * t + 1] = (_Float16)fast_tanh(a[3]);
        }
        f0h = p0.v; f1h = p1.v;   // D -> B in-register (pi layout)

        // ---- h1(p) = tanh(b1 + Wx1^T h0(p) + Wh1^T h1(p-1)) ----
        union PK q0, q1;
#pragma unroll
        for (int t = 0; t < 4; ++t) {
            f4v a = b1v[t];
            a = MFMA(wx[t][0], f0h, a);
            a = MFMA(wx[t][1], f1h, a);
            f4v b = MFMA(w1[t][0], f0g, z4);
            b = MFMA(w1[t][1], f1g, b);
            f4v s = a + b;
            vv[t][0] = fast_tanh(s[0]);
            vv[t][1] = fast_tanh(s[1]);
            vv[t][2] = fast_tanh(s[2]);
            vv[t][3] = fast_tanh(s[3]);
            q0.h[2 * t]     = (_Float16)vv[t][0];
            q0.h[2 * t + 1] = (_Float16)vv[t][1];
            q1.h[2 * t]     = (_Float16)vv[t][2];
            q1.h[2 * t + 1] = (_Float16)vv[t][3];
        }
        f0g = q0.v; f1g = q1.v;

#pragma unroll
        for (int t = 0; t < 4; ++t) xcs[t] = xns[t];
    }

    // Epilogue: out = sigmoid(h1(79) @ Wout + bout); lane holds 16 col-values
    // of row r16 (cols 16t+4g+q); reduce over the 4 g-groups via shfl.
    float pp = 0.f;
#pragma unroll
    for (int t = 0; t < 4; ++t) {
        f4v wov = *(const f4v*)&Wout[16 * t + 4 * g];
        pp = fmaf(vv[t][0], wov[0], pp);
        pp = fmaf(vv[t][1], wov[1], pp);
        pp = fmaf(vv[t][2], wov[2], pp);
        pp = fmaf(vv[t][3], wov[3], pp);
    }
    pp += __shfl_xor(pp, 16, 64);
    pp += __shfl_xor(pp, 32, 64);
    if (l < 16) {
        float logit = pp + bout[0];
        out[R + l] = __builtin_amdgcn_rcpf(
            1.0f + __builtin_amdgcn_exp2f(-1.4426950408889634f * logit));
    }
}

extern "C" void kernel_launch(void* const* d_in, const int* in_sizes, int n_in,
                              void* d_out, int out_size, void* d_ws, size_t ws_size,
                              hipStream_t stream) {
    const int*   tokens = (const int*)  d_in[0];
    const float* emb    = (const float*)d_in[1];
    const float* Wx0    = (const float*)d_in[2];
    const float* Wh0    = (const float*)d_in[3];
    const float* b0     = (const float*)d_in[4];
    const float* Wx1    = (const float*)d_in[5];
    const float* Wh1    = (const float*)d_in[6];
    const float* b1     = (const float*)d_in[7];
    const float* Wout   = (const float*)d_in[8];
    const float* bout   = (const float*)d_in[9];
    float* out  = (float*)d_out;
    _Float16* emb2h = (_Float16*)d_ws;   // VV*HH fp16 = 1.28 MB

    emb2_kernel<<<VV / 16, 256, 0, stream>>>(emb, Wx0, b0, emb2h);
    rnn_chain<<<BB / 16, 64, 0, stream>>>(tokens, emb2h, Wh0, Wx1, Wh1, b1,
                                          Wout, bout, out);
}

// Round 15
// 56.631 us; speedup vs baseline: 1.2977x; 1.2977x over previous
//
#include <hip/hip_runtime.h>

#define BB 4096
#define TT 80
#define VV 10000
#define EE 100
#define HH 64
#define STR 68   // fp16 row stride: 136 B/row; bursts at bank minimum (R6-verified)

typedef _Float16 f16x8 __attribute__((ext_vector_type(8)));
typedef _Float16 f16x4 __attribute__((ext_vector_type(4)));
typedef __attribute__((ext_vector_type(4))) float f4v;   // 4 fp32

// Transposed compute: D = A(W^T frag) * B(state frag) + C -> lane holds
// (batch row = l&15, 4 adjacent hidden cols = 4*(l>>4)+q)
#define MFMA(w, s, c) __builtin_amdgcn_mfma_f32_16x16x32_f16((w), (s), (c), 0, 0, 0)

// Raw barrier: drains LDS ops (lgkm) but lets global loads stay in flight.
#define BAR() do { asm volatile("s_waitcnt lgkmcnt(0)" ::: "memory"); \
                   __builtin_amdgcn_s_barrier();                      \
                   asm volatile("" ::: "memory"); } while (0)

// tanh(x) = 1 - 2/(exp(2x)+1). +inf -> 1, -inf -> -1.
__device__ __forceinline__ float fast_tanh(float x) {
    float e = __builtin_amdgcn_exp2f(x * 2.8853900817779268f); // exp(2x)
    return fmaf(-2.0f, __builtin_amdgcn_rcpf(e + 1.0f), 1.0f);
}

// hi-only fp16 weight A-fragment for W[k][c]: frag elem i <- W[32*kf+8*g+i][c].
// RNE error ~6e-5/elem -> pre-activation noise ~2.4e-4, same scale as the
// fp16-state noise (passing since R5; weights hi-only passing since R13).
__device__ __forceinline__ f16x8 load_wfrag_hi(const float* __restrict__ W, int kf,
                                               int g, int c) {
    union { _Float16 h[8]; f16x8 v; } th;
#pragma unroll
    for (int i = 0; i < 8; ++i)
        th.h[i] = (_Float16)W[(32 * kf + 8 * g + i) * HH + c];
    return th.v;
}

// emb2h[v][j] = fp16( b0[j] + sum_e emb[v][e] * Wx0[e][j] )  (unchanged, proven)
__global__ __launch_bounds__(256) void emb2_kernel(const float* __restrict__ emb,
                                                   const float* __restrict__ Wx0,
                                                   const float* __restrict__ b0,
                                                   _Float16* __restrict__ emb2h) {
    const int tid = threadIdx.x;
    const int wid = tid >> 6;
    const int l = tid & 63;
    const int g = l >> 4;
    const int r16 = l & 15;
    const int c = 16 * wid + r16;
    const int jcol = 16 * wid + 4 * g;
    const int vr = blockIdx.x * 16 + r16;   // VV % 16 == 0

    f16x8 wa[4];   // Wx0^T hi frags, K = 128 (zero-pad e >= 100)
#pragma unroll
    for (int kf = 0; kf < 4; ++kf) {
        union { _Float16 h[8]; f16x8 v; } t;
#pragma unroll
        for (int i = 0; i < 8; ++i) {
            int e = 32 * kf + 8 * g + i;
            t.h[i] = (e < EE) ? (_Float16)Wx0[e * HH + c] : (_Float16)0.f;
        }
        wa[kf] = t.v;
    }
    const float* er = emb + (size_t)vr * EE;
    f4v acc = *(const f4v*)&b0[jcol];
#pragma unroll
    for (int kf = 0; kf < 4; ++kf) {
        union { _Float16 h[8]; f16x8 v; } tb;
#pragma unroll
        for (int i = 0; i < 8; ++i) {
            int e = 32 * kf + 8 * g + i;
            tb.h[i] = (e < EE) ? (_Float16)er[e] : (_Float16)0.f;
        }
        acc = MFMA(wa[kf], tb.v, acc);
    }
    f16x4 o;
#pragma unroll
    for (int q = 0; q < 4; ++q) o[q] = (_Float16)acc[q];
    *(f16x4*)&emb2h[(size_t)vr * HH + jcol] = o;
}

// R13 structure + s_setprio on the recurrence-critical cluster: 256 blocks x
// 512 thr (8 waves = 2/SIMD, one L0 + one L1 per SIMD), 16 rows/block.
// Waves 0-3 (L0): h0(p) = tanh(x(p) + Wh0^T h0(p-1))                [2 MFMA]
// Waves 4-7 (L1): h1(p-1) = tanh(b1 + Wx1^T h0(p-1) + Wh1^T h1(p-2)) [4 MFMA]
// fp16 state in double-buffered LDS; one raw barrier per phase; 81 phases.
// setprio(1) wraps each role's MFMA+tanh+store cluster (T5: pays only with
// role-diverse waves per SIMD, which this structure has).
__global__ __launch_bounds__(512, 1) void rnn_pipe(
    const int* __restrict__ tokens, const _Float16* __restrict__ emb2,
    const float* __restrict__ Wh0, const float* __restrict__ Wx1,
    const float* __restrict__ Wh1, const float* __restrict__ b1,
    const float* __restrict__ Wout, const float* __restrict__ bout,
    float* __restrict__ out) {
    __shared__ __align__(16) _Float16 H0[2][16][STR];
    __shared__ __align__(16) _Float16 H1[2][16][STR];
    __shared__ __align__(16) int tokT[TT][16];   // [t][row], byte-scaled (<<7)
    __shared__ float Pred[4][16];

    const int tid = threadIdx.x;
    const int w8 = tid >> 6;         // 0..7
    const int l = tid & 63;
    const int g = l >> 4;
    const int r16 = l & 15;          // my batch row
    const bool isL0 = (w8 < 4);
    const int tile = isL0 ? w8 : (w8 - 4);
    const int c = 16 * tile + r16;   // weight column for A-fragment loads
    const int jcol = 16 * tile + 4 * g;  // my 4 output cols
    const int R = blockIdx.x * 16;   // base batch row

    for (int i = tid; i < 16 * TT; i += 512) {
        int r = i / TT, t = i - r * TT;              // coalesced global read
        tokT[t][r] = tokens[R * TT + i] << 7;        // row stride 64 fp16 = 128 B
    }

    // Role weights (hi-only): L0 -> wA = Wh0; L1 -> wA = Wx1, wB = Wh1.
    f16x8 wA[2], wB[2];
    if (isL0) {
        wA[0] = load_wfrag_hi(Wh0, 0, g, c);
        wA[1] = load_wfrag_hi(Wh0, 1, g, c);
        wB[0] = wB[1] = (f16x8)0;
    } else {
        wA[0] = load_wfrag_hi(Wx1, 0, g, c);
        wA[1] = load_wfrag_hi(Wx1, 1, g, c);
        wB[0] = load_wfrag_hi(Wh1, 0, g, c);
        wB[1] = load_wfrag_hi(Wh1, 1, g, c);
    }
    const f4v b1v = *(const f4v*)&b1[jcol];
    const f4v wov = *(const f4v*)&Wout[jcol];
    const f4v z4 = {0.f, 0.f, 0.f, 0.f};
    const char* ebase = (const char*)emb2 + (size_t)jcol * 2;

    BAR();   // tokens staged

    f16x8 a0[2] = {(f16x8)0, (f16x8)0};   // h0(p-1) fragments (kf=0,1)
    f16x8 a1[2] = {(f16x8)0, (f16x8)0};   // h1(p-2) fragments (L1 only)

    f16x4 xc = (f16x4)0, xn = (f16x4)0;   // raw fp16 gathers (L0 only)
    if (isL0) {
        xc = *(const f16x4*)(ebase + tokT[0][r16]);
        xn = *(const f16x4*)(ebase + tokT[1][r16]);
        // ---- phase 0: h0(0) = tanh(x0) ----
        f16x4 ph;
#pragma unroll
        for (int q = 0; q < 4; ++q) ph[q] = (_Float16)fast_tanh((float)xc[q]);
        *(f16x4*)&H0[0][r16][jcol] = ph;           // one b64 write
        xc = xn;
    }
    BAR();
    a0[0] = *(const f16x8*)&H0[0][r16][8 * g];
    a0[1] = *(const f16x8*)&H0[0][r16][32 + 8 * g];
    // a1 stays zero (h1(-1) = 0); H1[0] not yet written -> do not read it.

    // ---- main loop p = 1..TT-1 (par = p&1) ----
#pragma unroll 2
    for (int p = 1; p <= TT - 1; ++p) {
        const int par = p & 1;
        if (isL0) {
            // prefetch x(p+1); floats across BAR to next-phase use
            if (p + 1 <= TT - 1)
                xn = *(const f16x4*)(ebase + tokT[p + 1][r16]);
            // h0(p): single chain of 2 — the recurrence-critical cluster
            __builtin_amdgcn_s_setprio(1);
            f4v A1 = {(float)xc[0], (float)xc[1], (float)xc[2], (float)xc[3]};
            A1 = MFMA(wA[0], a0[0], A1);
            A1 = MFMA(wA[1], a0[1], A1);
            f16x4 p0;
#pragma unroll
            for (int q = 0; q < 4; ++q) p0[q] = (_Float16)fast_tanh(A1[q]);
            *(f16x4*)&H0[par][r16][jcol] = p0;
            __builtin_amdgcn_s_setprio(0);
            xc = xn;
        } else {
            // h1(p-1): 2 chains of 2 — critical cluster
            __builtin_amdgcn_s_setprio(1);
            f4v C1 = b1v;
            C1 = MFMA(wA[0], a0[0], C1);
            C1 = MFMA(wA[1], a0[1], C1);
            f4v C3 = MFMA(wB[0], a1[0], z4);
            C3 = MFMA(wB[1], a1[1], C3);
            f4v acc1 = C1 + C3;
            f16x4 p1;
#pragma unroll
            for (int q = 0; q < 4; ++q) p1[q] = (_Float16)fast_tanh(acc1[q]);
            *(f16x4*)&H1[par][r16][jcol] = p1;
            __builtin_amdgcn_s_setprio(0);
        }
        BAR();
        a0[0] = *(const f16x8*)&H0[par][r16][8 * g];
        a0[1] = *(const f16x8*)&H0[par][r16][32 + 8 * g];
        if (!isL0) {
            a1[0] = *(const f16x8*)&H1[par][r16][8 * g];
            a1[1] = *(const f16x8*)&H1[par][r16][32 + 8 * g];
        }
    }

    // ---- p = TT = 80: L1 only -> h1(79) stays in registers; epilogue ----
    if (!isL0) {
        f4v C1 = b1v;
        C1 = MFMA(wA[0], a0[0], C1);
        C1 = MFMA(wA[1], a0[1], C1);
        f4v C3 = MFMA(wB[0], a1[0], z4);
        C3 = MFMA(wB[1], a1[1], C3);
        f4v acc1 = C1 + C3;
        // out = sigmoid(h1(79) @ Wout + bout): lane holds 4 cols of row r16
        float pp = fast_tanh(acc1[0]) * wov[0];
        pp = fmaf(fast_tanh(acc1[1]), wov[1], pp);
        pp = fmaf(fast_tanh(acc1[2]), wov[2], pp);
        pp = fmaf(fast_tanh(acc1[3]), wov[3], pp);
        pp += __shfl_xor(pp, 16, 64);   // sum over g-groups
        pp += __shfl_xor(pp, 32, 64);
        if (l < 16) Pred[tile][l] = pp;
    }
    BAR();
    if (tid < 16) {
        float logit = Pred[0][tid] + Pred[1][tid] + Pred[2][tid] +
                      Pred[3][tid] + bout[0];
        out[R + tid] = __builtin_amdgcn_rcpf(
            1.0f + __builtin_amdgcn_exp2f(-1.4426950408889634f * logit));
    }
}

extern "C" void kernel_launch(void* const* d_in, const int* in_sizes, int n_in,
                              void* d_out, int out_size, void* d_ws, size_t ws_size,
                              hipStream_t stream) {
    const int*   tokens = (const int*)  d_in[0];
    const float* emb    = (const float*)d_in[1];
    const float* Wx0    = (const float*)d_in[2];
    const float* Wh0    = (const float*)d_in[3];
    const float* b0     = (const float*)d_in[4];
    const float* Wx1    = (const float*)d_in[5];
    const float* Wh1    = (const float*)d_in[6];
    const float* b1     = (const float*)d_in[7];
    const float* Wout   = (const float*)d_in[8];
    const float* bout   = (const float*)d_in[9];
    float* out  = (float*)d_out;
    _Float16* emb2h = (_Float16*)d_ws;   // VV*HH fp16 = 1.28 MB

    emb2_kernel<<<VV / 16, 256, 0, stream>>>(emb, Wx0, b0, emb2h);
    rnn_pipe<<<BB / 16, 512, 0, stream>>>(tokens, emb2h, Wh0, Wx1, Wh1, b1,
                                          Wout, bout, out);
}

// Round 16
// 38.151 us; speedup vs baseline: 1.9263x; 1.4844x over previous
//
#include <hip/hip_runtime.h>

#define BB 4096
#define TT 80
#define VV 10000
#define EE 100
#define HH 64
#define STR 68   // fp16 row stride: 136 B/row; bursts at bank minimum (R6-verified)

typedef _Float16 f16x8 __attribute__((ext_vector_type(8)));
typedef _Float16 f16x4 __attribute__((ext_vector_type(4)));
typedef __attribute__((ext_vector_type(4))) float f4v;   // 4 fp32

// Transposed compute: D = A(W^T frag) * B(state frag) + C -> lane holds
// (batch row = l&15, 4 adjacent hidden cols = 4*(l>>4)+q)
#define MFMA(w, s, c) __builtin_amdgcn_mfma_f32_16x16x32_f16((w), (s), (c), 0, 0, 0)

// Raw barrier: drains LDS ops (lgkm) but lets global loads stay in flight.
#define BAR() do { asm volatile("s_waitcnt lgkmcnt(0)" ::: "memory"); \
                   __builtin_amdgcn_s_barrier();                      \
                   asm volatile("" ::: "memory"); } while (0)

// tanh(x) = 1 - 2/(exp(2x)+1). +inf -> 1, -inf -> -1.
__device__ __forceinline__ float fast_tanh(float x) {
    float e = __builtin_amdgcn_exp2f(x * 2.8853900817779268f); // exp(2x)
    return 1.0f - 2.0f * __builtin_amdgcn_rcpf(e + 1.0f);
}

// hi-only fp16 weight A-fragment for W[k][c]: frag elem i <- W[32*kf+8*g+i][c].
// RNE error ~6e-5/elem -> pre-activation noise ~2.4e-4, same scale as the
// fp16-state noise (passing since R5; weights hi-only passing since R13).
__device__ __forceinline__ f16x8 load_wfrag_hi(const float* __restrict__ W, int kf,
                                               int g, int c) {
    union { _Float16 h[8]; f16x8 v; } th;
#pragma unroll
    for (int i = 0; i < 8; ++i)
        th.h[i] = (_Float16)W[(32 * kf + 8 * g + i) * HH + c];
    return th.v;
}

// emb2h[v][j] = fp16( b0[j] + sum_e emb[v][e] * Wx0[e][j] )  (unchanged, proven)
__global__ __launch_bounds__(256) void emb2_kernel(const float* __restrict__ emb,
                                                   const float* __restrict__ Wx0,
                                                   const float* __restrict__ b0,
                                                   _Float16* __restrict__ emb2h) {
    const int tid = threadIdx.x;
    const int wid = tid >> 6;
    const int l = tid & 63;
    const int g = l >> 4;
    const int r16 = l & 15;
    const int c = 16 * wid + r16;
    const int jcol = 16 * wid + 4 * g;
    const int vr = blockIdx.x * 16 + r16;   // VV % 16 == 0

    f16x8 wa[4];   // Wx0^T hi frags, K = 128 (zero-pad e >= 100)
#pragma unroll
    for (int kf = 0; kf < 4; ++kf) {
        union { _Float16 h[8]; f16x8 v; } t;
#pragma unroll
        for (int i = 0; i < 8; ++i) {
            int e = 32 * kf + 8 * g + i;
            t.h[i] = (e < EE) ? (_Float16)Wx0[e * HH + c] : (_Float16)0.f;
        }
        wa[kf] = t.v;
    }
    const float* er = emb + (size_t)vr * EE;
    f4v acc = *(const f4v*)&b0[jcol];
#pragma unroll
    for (int kf = 0; kf < 4; ++kf) {
        union { _Float16 h[8]; f16x8 v; } tb;
#pragma unroll
        for (int i = 0; i < 8; ++i) {
            int e = 32 * kf + 8 * g + i;
            tb.h[i] = (e < EE) ? (_Float16)er[e] : (_Float16)0.f;
        }
        acc = MFMA(wa[kf], tb.v, acc);
    }
    f16x4 o;
#pragma unroll
    for (int q = 0; q < 4; ++q) o[q] = (_Float16)acc[q];
    *(f16x4*)&emb2h[(size_t)vr * HH + jcol] = o;
}

// R13 structure (exact revert of the measured-best kernel): 256 blocks x 512
// thr (8 waves = 2/SIMD), 16 rows/block.
// Waves 0-3 (L0): h0(p) = tanh(x(p) + Wh0^T h0(p-1))                [2 MFMA]
// Waves 4-7 (L1): h1(p-1) = tanh(b1 + Wx1^T h0(p-1) + Wh1^T h1(p-2)) [4 MFMA]
// fp16 state in double-buffered LDS; one raw barrier per phase; 81 phases.
// NOTE: no s_setprio — R15 measured it at -16 µs here (priority inversion
// between barrier-lockstep role waves on the same SIMD).
__global__ __launch_bounds__(512, 1) void rnn_pipe(
    const int* __restrict__ tokens, const _Float16* __restrict__ emb2,
    const float* __restrict__ Wh0, const float* __restrict__ Wx1,
    const float* __restrict__ Wh1, const float* __restrict__ b1,
    const float* __restrict__ Wout, const float* __restrict__ bout,
    float* __restrict__ out) {
    __shared__ __align__(16) _Float16 H0[2][16][STR];
    __shared__ __align__(16) _Float16 H1[2][16][STR];
    __shared__ __align__(16) int tokT[TT][16];   // [t][row], byte-scaled (<<7)
    __shared__ float Pred[4][16];

    const int tid = threadIdx.x;
    const int w8 = tid >> 6;         // 0..7
    const int l = tid & 63;
    const int g = l >> 4;
    const int r16 = l & 15;          // my batch row
    const bool isL0 = (w8 < 4);
    const int tile = isL0 ? w8 : (w8 - 4);
    const int c = 16 * tile + r16;   // weight column for A-fragment loads
    const int jcol = 16 * tile + 4 * g;  // my 4 output cols
    const int R = blockIdx.x * 16;   // base batch row

    for (int i = tid; i < 16 * TT; i += 512) {
        int r = i / TT, t = i - r * TT;              // coalesced global read
        tokT[t][r] = tokens[R * TT + i] << 7;        // row stride 64 fp16 = 128 B
    }

    // Role weights (hi-only): L0 -> wA = Wh0; L1 -> wA = Wx1, wB = Wh1.
    f16x8 wA[2], wB[2];
    if (isL0) {
        wA[0] = load_wfrag_hi(Wh0, 0, g, c);
        wA[1] = load_wfrag_hi(Wh0, 1, g, c);
        wB[0] = wB[1] = (f16x8)0;
    } else {
        wA[0] = load_wfrag_hi(Wx1, 0, g, c);
        wA[1] = load_wfrag_hi(Wx1, 1, g, c);
        wB[0] = load_wfrag_hi(Wh1, 0, g, c);
        wB[1] = load_wfrag_hi(Wh1, 1, g, c);
    }
    const f4v b1v = *(const f4v*)&b1[jcol];
    const f4v wov = *(const f4v*)&Wout[jcol];
    const f4v z4 = {0.f, 0.f, 0.f, 0.f};
    const char* ebase = (const char*)emb2 + (size_t)jcol * 2;

    BAR();   // tokens staged

    f16x8 a0[2] = {(f16x8)0, (f16x8)0};   // h0(p-1) fragments (kf=0,1)
    f16x8 a1[2] = {(f16x8)0, (f16x8)0};   // h1(p-2) fragments (L1 only)

    f16x4 xc = (f16x4)0, xn = (f16x4)0;   // raw fp16 gathers (L0 only)
    if (isL0) {
        xc = *(const f16x4*)(ebase + tokT[0][r16]);
        xn = *(const f16x4*)(ebase + tokT[1][r16]);
        // ---- phase 0: h0(0) = tanh(x0) ----
        f16x4 ph;
#pragma unroll
        for (int q = 0; q < 4; ++q) ph[q] = (_Float16)fast_tanh((float)xc[q]);
        *(f16x4*)&H0[0][r16][jcol] = ph;           // one b64 write
        xc = xn;
    }
    BAR();
    a0[0] = *(const f16x8*)&H0[0][r16][8 * g];
    a0[1] = *(const f16x8*)&H0[0][r16][32 + 8 * g];
    // a1 stays zero (h1(-1) = 0); H1[0] not yet written -> do not read it.

    // ---- main loop p = 1..TT-1 (par = p&1) ----
#pragma unroll 2
    for (int p = 1; p <= TT - 1; ++p) {
        const int par = p & 1;
        if (isL0) {
            // prefetch x(p+1) (clamped; x(TT-1) redundant re-gather at p=79)
            int pn = (p + 1 <= TT - 1) ? p + 1 : TT - 1;
            xn = *(const f16x4*)(ebase + tokT[pn][r16]);
            // h0(p): single chain of 2
            f4v A1 = {(float)xc[0], (float)xc[1], (float)xc[2], (float)xc[3]};
            A1 = MFMA(wA[0], a0[0], A1);
            A1 = MFMA(wA[1], a0[1], A1);
            f16x4 p0;
#pragma unroll
            for (int q = 0; q < 4; ++q) p0[q] = (_Float16)fast_tanh(A1[q]);
            *(f16x4*)&H0[par][r16][jcol] = p0;
            xc = xn;
        } else {
            // h1(p-1): 2 chains of 2
            f4v C1 = b1v;
            C1 = MFMA(wA[0], a0[0], C1);
            C1 = MFMA(wA[1], a0[1], C1);
            f4v C3 = MFMA(wB[0], a1[0], z4);
            C3 = MFMA(wB[1], a1[1], C3);
            f4v acc1 = C1 + C3;
            f16x4 p1;
#pragma unroll
            for (int q = 0; q < 4; ++q) p1[q] = (_Float16)fast_tanh(acc1[q]);
            *(f16x4*)&H1[par][r16][jcol] = p1;
        }
        BAR();
        a0[0] = *(const f16x8*)&H0[par][r16][8 * g];
        a0[1] = *(const f16x8*)&H0[par][r16][32 + 8 * g];
        if (!isL0) {
            a1[0] = *(const f16x8*)&H1[par][r16][8 * g];
            a1[1] = *(const f16x8*)&H1[par][r16][32 + 8 * g];
        }
    }

    // ---- p = TT = 80: L1 only -> h1(79) stays in registers; epilogue ----
    if (!isL0) {
        f4v C1 = b1v;
        C1 = MFMA(wA[0], a0[0], C1);
        C1 = MFMA(wA[1], a0[1], C1);
        f4v C3 = MFMA(wB[0], a1[0], z4);
        C3 = MFMA(wB[1], a1[1], C3);
        f4v acc1 = C1 + C3;
        // out = sigmoid(h1(79) @ Wout + bout): lane holds 4 cols of row r16
        float pp = fast_tanh(acc1[0]) * wov[0];
        pp = fmaf(fast_tanh(acc1[1]), wov[1], pp);
        pp = fmaf(fast_tanh(acc1[2]), wov[2], pp);
        pp = fmaf(fast_tanh(acc1[3]), wov[3], pp);
        pp += __shfl_xor(pp, 16, 64);   // sum over g-groups
        pp += __shfl_xor(pp, 32, 64);
        if (l < 16) Pred[tile][l] = pp;
    }
    BAR();
    if (tid < 16) {
        float logit = Pred[0][tid] + Pred[1][tid] + Pred[2][tid] +
                      Pred[3][tid] + bout[0];
        out[R + tid] = __builtin_amdgcn_rcpf(
            1.0f + __builtin_amdgcn_exp2f(-1.4426950408889634f * logit));
    }
}

extern "C" void kernel_launch(void* const* d_in, const int* in_sizes, int n_in,
                              void* d_out, int out_size, void* d_ws, size_t ws_size,
                              hipStream_t stream) {
    const int*   tokens = (const int*)  d_in[0];
    const float* emb    = (const float*)d_in[1];
    const float* Wx0    = (const float*)d_in[2];
    const float* Wh0    = (const float*)d_in[3];
    const float* b0     = (const float*)d_in[4];
    const float* Wx1    = (const float*)d_in[5];
    const float* Wh1    = (const float*)d_in[6];
    const float* b1     = (const float*)d_in[7];
    const float* Wout   = (const float*)d_in[8];
    const float* bout   = (const float*)d_in[9];
    float* out  = (float*)d_out;
    _Float16* emb2h = (_Float16*)d_ws;   // VV*HH fp16 = 1.28 MB

    emb2_kernel<<<VV / 16, 256, 0, stream>>>(emb, Wx0, b0, emb2h);
    rnn_pipe<<<BB / 16, 512, 0, stream>>>(tokens, emb2h, Wh0, Wx1, Wh1, b1,
                                          Wout, bout, out);
}